// Round 6
// baseline (267.880 us; speedup 1.0000x reference)
//
#include <hip/hip_runtime.h>
#include <math.h>

#define NQ 16
#define NLAYERS 3
#define NSTATES 65536   // 2^16
#define BATCH 256

// Clamped global read: any harness/size mismatch becomes a wrong value,
// never an OOB fault.
__device__ __forceinline__ float rd(const float* __restrict__ p, int i, int n) {
    return p[i < n ? i : (n - 1)];
}

// ---------------------------------------------------------------------------
// static_for with compile-time indices (keeps every state subscript literal).
// ---------------------------------------------------------------------------
template <int I> struct IC { static constexpr int v = I; };

template <int I, int N, typename F>
__device__ __forceinline__ void sfor_i(F& f) {
    if constexpr (I < N) {
        f(IC<I>{});
        sfor_i<I + 1, N>(f);
    }
}
template <int N, typename F>
__device__ __forceinline__ void sfor(F&& f) { sfor_i<0, N>(f); }

// noisy-CNOT symmetric mix: a' = (1-p)a + pb ; b' = (1-p)b + pa
__device__ __forceinline__ void mix2(float& a, float& b, float p) {
    float na = (1.f - p) * a + p * b;
    float nb = (1.f - p) * b + p * a;
    a = na; b = nb;
}
// asymmetric variant with precomputed per-lane coeffs (lane-dependent ctrl)
__device__ __forceinline__ void mixc(float& a, float& b, float qc, float pc) {
    float na = qc * a + pc * b;
    float nb = qc * b + pc * a;
    a = na; b = nb;
}
// single-qubit butterfly on a pair (a0 = bit clear, a1 = bit set)
__device__ __forceinline__ void bf2(float& a0, float& a1, float4 m) {
    float n0 = m.x * a0 + m.y * a1;
    float n1 = m.z * a0 + m.w * a1;
    a0 = n0; a1 = n1;
}

// ---------------------------------------------------------------------------
// Swizzled LDS state address: column rotated by row so BOTH access patterns
// are conflict-free:
//   natural (col = tid, any row): lanes consecutive -> 2/bank, free
//   row-segment (fixed row, 16 consecutive cols): banks = (l&15)+16*l4 -> free
// ---------------------------------------------------------------------------
__device__ __forceinline__ int ladr(int row, int col) {
    return row * 1024 + ((col + row) & 1023);
}

// ---------------------------------------------------------------------------
// R6: R5 measured DS-issue-bound (512 b32 + 704 bperm per thread-layer).
// This round cuts bperm 704 -> 464 and restructures passes:
//  - S3: LDS-half lane gates via row-segment RMW (16 consecutive floats hold
//    all b3..b0) -> q0..3, c0..2 free VALU; only q4/q5/c3/c4 shfl (56/pass-set
//    vs 352). Needs the ladr column swizzle.
//  - T1 now fuses c5..8 (G-bit-local in layout B) -> R5's [B] window deleted.
//  - c13/c14 defer into next layer's S2 passA (exact order kept) or into the
//    fused output pass for the last layer.
//  - Layer 0: LDS half is zero until T1's scatter -> skip S2/S3/vL reads and
//    the zero-init entirely.
// Layout A: row = (b14,b13..b10) (+reg slots for b15=0), col = tid.
// Layout B (between T1/T2): row/slot = (b14, b9..b6), col = (b13..b10,b5..b0).
// ---------------------------------------------------------------------------
__global__
__attribute__((amdgpu_flat_work_group_size(1024, 1024)))
void qsim(const float* __restrict__ x,
          const float* __restrict__ rot,
          const float* __restrict__ ent,
          const float* __restrict__ W1,
          const float* __restrict__ b1,
          const float* __restrict__ W2,
          const float* __restrict__ b2,
          float* __restrict__ out,
          long long out_floats,
          int nx, int nrot, int nent, int nW1, int nb1, int nW2, int nb2) {
    const int tid  = threadIdx.x;
    const int b    = blockIdx.x;
    const int lane = tid & 63;
    const int wave = tid >> 6;
    const int wq   = (tid >> 8) & 3;  // transpose round selector
    const int wv   = (tid >> 6) & 3;  // transpose v-index

    __shared__ float  ldsS[32 * 1024];         // 128 KiB: b15=1 half of state
    __shared__ float  scr[4 * 1024];           // 16 KiB transpose bounce
    __shared__ float4 Mg[NLAYERS * NQ];        // 48 gate matrices
    __shared__ float  pg[NLAYERS * (NQ - 1)];  // 45 CNOT mix probs
    __shared__ float  hidS[64];
    __shared__ float  hqS[16];

    // ---- Phase A: MLP hidden layer (64 threads) + sigmoid probs ----
    if (tid < 64) {
        float s = rd(b1, tid, nb1);
        for (int k = 0; k < 100; k++)
            s = fmaf(rd(x, b * 100 + k, nx), rd(W1, k * 64 + tid, nW1), s);
        hidS[tid] = fmaxf(s, 0.f);
    } else if (tid >= 64 && tid < 64 + NLAYERS * (NQ - 1)) {
        int i = tid - 64;
        pg[i] = 1.f / (1.f + expf(-rd(ent, i, nent)));
    }
    __syncthreads();

    // ---- Phase B: output layer hq (16 threads) ----
    if (tid < 16) {
        float s = rd(b2, tid, nb2);
#pragma unroll
        for (int i = 0; i < 64; i++)
            s = fmaf(hidS[i], rd(W2, i * 16 + tid, nW2), s);
        hqS[tid] = tanhf(s);
    }
    __syncthreads();

    // ---- Phase C: gate matrices (48 threads) ----
    if (tid < NLAYERS * NQ) {
        int q = tid & 15;
        float hv = hqS[q];
        float a0 = 0.5f * rd(rot, tid * 3 + 0, nrot) * hv;
        float a1 = 0.5f * rd(rot, tid * 3 + 1, nrot) * hv;
        float a2 = 0.5f * rd(rot, tid * 3 + 2, nrot) * hv;
        float cx = cosf(a0), sx = sinf(a0);
        float cy = cosf(a1), sy = sinf(a1);
        float cz = cosf(a2), sz = sinf(a2);
        Mg[tid] = make_float4(cx * cy * cz, -(sx * sy * sz),
                              sx * sy * cz,  cx * cy * sz);
    }
    __syncthreads();

    // ---- statevector init: |0...0> ----
    // NOTE: ldsS deliberately NOT zero-initialized: layer 0 never reads it;
    // T1's scatter (l=0) writes every row before any read.
    float r[32];
    sfor<32>([&](auto J) { r[J.v] = 0.f; });
    if (tid == 0) r[0] = 1.f;

    for (int l = 0; l < NLAYERS; l++) {
        // ======== S2: prev-layer c13/c14 + this layer's q10..14 ========
        if (l > 0) {
            float p13p = pg[(l - 1) * 15 + 13];
            float p14p = pg[(l - 1) * 15 + 14];
            // reg-half c13 (b13=1): r[8..15] <-> r[24..31]
            sfor<8>([&](auto K) { mix2(r[8 + K.v], r[24 + K.v], p13p); });
            float4 m13 = Mg[l * NQ + 13];
            float4 m14 = Mg[l * NQ + 14];
            // passA: 4-row windows {w, w+8, w+16, w+24}: c13(lds), c14, q13, q14
            sfor<8>([&](auto W) {
                float t0 = ldsS[ladr(W.v,      tid)];
                float t1 = ldsS[ladr(W.v + 8,  tid)];
                float t2 = ldsS[ladr(W.v + 16, tid)];
                float t3 = ldsS[ladr(W.v + 24, tid)];
                mix2(t1, t3, p13p);               // c13 lds: rows 8..15<->24..31
                mix2(r[W.v + 16], t2, p14p);      // c14: reg s <-> lds row s (b14=1)
                mix2(r[W.v + 24], t3, p14p);
                bf2(t0, t1, m13); bf2(t2, t3, m13);   // q13
                bf2(t0, t2, m14); bf2(t1, t3, m14);   // q14
                ldsS[ladr(W.v,      tid)] = t0;
                ldsS[ladr(W.v + 8,  tid)] = t1;
                ldsS[ladr(W.v + 16, tid)] = t2;
                ldsS[ladr(W.v + 24, tid)] = t3;
            });
            // reg q13, q14 (after c14 touched r[16..31])
            sfor<8>([&](auto K) { bf2(r[K.v],      r[K.v + 8],  m13); });
            sfor<8>([&](auto K) { bf2(r[K.v + 16], r[K.v + 24], m13); });
            sfor<16>([&](auto K) { bf2(r[K.v], r[K.v + 16], m14); });
            // passB: 8-row windows: q10..12 (lds)
            sfor<4>([&](auto W) {
                float t[8];
                sfor<8>([&](auto K) { t[K.v] = ldsS[ladr(W.v * 8 + K.v, tid)]; });
                sfor<3>([&](auto QQ) {
                    float4 m = Mg[l * NQ + 10 + QQ.v];
                    sfor<8>([&](auto K) {
                        constexpr int h = 1 << QQ.v;
                        if constexpr (!(K.v & h)) bf2(t[K.v], t[K.v | h], m);
                    });
                });
                sfor<8>([&](auto K) { ldsS[ladr(W.v * 8 + K.v, tid)] = t[K.v]; });
            });
            // reg q10..12
            sfor<3>([&](auto QQ) {
                float4 m = Mg[l * NQ + 10 + QQ.v];
                sfor<32>([&](auto J) {
                    constexpr int h = 1 << QQ.v;
                    if constexpr (!(J.v & h)) bf2(r[J.v], r[J.v | h], m);
                });
            });
        } else {
            // l == 0: LDS half identically zero; reg-only q10..14
            sfor<5>([&](auto QQ) {
                float4 m = Mg[10 + QQ.v];
                sfor<32>([&](auto J) {
                    constexpr int h = 1 << QQ.v;
                    if constexpr (!(J.v & h)) bf2(r[J.v], r[J.v | h], m);
                });
            });
        }

        // ======== reg lane pass: rot q0..5 then cnot c0..4 (shfl) ========
#pragma unroll
        for (int q = 0; q < 6; q++) {
            float4 m = Mg[l * NQ + q];
            int bit = (tid >> q) & 1;
            float cown  = bit ? m.w : m.x;
            float cpart = bit ? m.z : m.y;
            sfor<4>([&](auto C) {
                sfor<8>([&](auto K) {
                    constexpr int j = C.v * 8 + K.v;
                    float part = __shfl_xor(r[j], 1 << q);
                    r[j] = cown * r[j] + cpart * part;
                });
                __builtin_amdgcn_sched_barrier(0);
            });
        }
#pragma unroll
        for (int c = 0; c < 5; c++) {
            float p = pg[l * 15 + c];
            int ctl = (tid >> c) & 1;
            float pc = ctl ? p : 0.f;
            float qc = ctl ? (1.f - p) : 1.f;
            sfor<4>([&](auto C) {
                sfor<8>([&](auto K) {
                    constexpr int j = C.v * 8 + K.v;
                    float f = __shfl_xor(r[j], 1 << (c + 1));
                    r[j] = qc * r[j] + pc * f;
                });
                __builtin_amdgcn_sched_barrier(0);
            });
        }

        // ======== S3: LDS-half lane gates via row-segment RMW ========
        // v[j] (j = b3..b0) are 16 consecutive (swizzled) floats of one row.
        // q0..3, c0..2 free; q4/q5/c3/c4 via shfl on lane bits 4/5.
        if (l > 0) {
            __syncthreads();   // passB writes -> cross-column reads
            const int Rlow  = tid & 15;
            const int Cbase = tid & 0x3F0;
            const int bit4  = (tid >> 4) & 1;
            const int bit5  = (tid >> 5) & 1;
            sfor<2>([&](auto H) {
                const int R    = H.v * 16 + Rlow;
                const int base = R * 1024;
                const int cb   = Cbase + R;
                float v[16];
                sfor<16>([&](auto J) { v[J.v] = ldsS[base + ((cb + J.v) & 1023)]; });
                // rot q0..3 (slot bits)
                sfor<4>([&](auto Q) {
                    float4 m = Mg[l * NQ + Q.v];
                    sfor<16>([&](auto J) {
                        constexpr int h = 1 << Q.v;
                        if constexpr (!(J.v & h)) bf2(v[J.v], v[J.v | h], m);
                    });
                });
                // rot q4 (lane bit 4)
                {
                    float4 m = Mg[l * NQ + 4];
                    float cown  = bit4 ? m.w : m.x;
                    float cpart = bit4 ? m.z : m.y;
                    sfor<2>([&](auto C) {
                        sfor<8>([&](auto K) {
                            constexpr int j = C.v * 8 + K.v;
                            float part = __shfl_xor(v[j], 16);
                            v[j] = cown * v[j] + cpart * part;
                        });
                        __builtin_amdgcn_sched_barrier(0);
                    });
                }
                // rot q5 (lane bit 5)
                {
                    float4 m = Mg[l * NQ + 5];
                    float cown  = bit5 ? m.w : m.x;
                    float cpart = bit5 ? m.z : m.y;
                    sfor<2>([&](auto C) {
                        sfor<8>([&](auto K) {
                            constexpr int j = C.v * 8 + K.v;
                            float part = __shfl_xor(v[j], 32);
                            v[j] = cown * v[j] + cpart * part;
                        });
                        __builtin_amdgcn_sched_barrier(0);
                    });
                }
                // c0: ctrl b0, tgt b1
                {
                    float p = pg[l * 15 + 0];
                    sfor<16>([&](auto J) {
                        if constexpr ((J.v & 1) && !(J.v & 2)) mix2(v[J.v], v[J.v | 2], p);
                    });
                }
                // c1: ctrl b1, tgt b2
                {
                    float p = pg[l * 15 + 1];
                    sfor<16>([&](auto J) {
                        if constexpr ((J.v & 2) && !(J.v & 4)) mix2(v[J.v], v[J.v | 4], p);
                    });
                }
                // c2: ctrl b2, tgt b3
                {
                    float p = pg[l * 15 + 2];
                    sfor<16>([&](auto J) {
                        if constexpr ((J.v & 4) && !(J.v & 8)) mix2(v[J.v], v[J.v | 8], p);
                    });
                }
                // c3: ctrl b3 (slot), tgt b4 (lane): only j>=8 participate
                {
                    float p = pg[l * 15 + 3];
                    sfor<8>([&](auto K) {
                        constexpr int j = 8 + K.v;
                        float f = __shfl_xor(v[j], 16);
                        v[j] = (1.f - p) * v[j] + p * f;
                    });
                    __builtin_amdgcn_sched_barrier(0);
                }
                // c4: ctrl b4 (lane), tgt b5 (lane)
                {
                    float p = pg[l * 15 + 4];
                    float pc = bit4 ? p : 0.f;
                    float qc = bit4 ? (1.f - p) : 1.f;
                    sfor<2>([&](auto C) {
                        sfor<8>([&](auto K) {
                            constexpr int j = C.v * 8 + K.v;
                            float f = __shfl_xor(v[j], 32);
                            v[j] = qc * v[j] + pc * f;
                        });
                        __builtin_amdgcn_sched_barrier(0);
                    });
                }
                sfor<16>([&](auto J) { ldsS[base + ((cb + J.v) & 1023)] = v[J.v]; });
            });
        }

        // ======== T1: A->B transpose, fused q6..9, q15, c5..8 ========
        {
            float p5 = pg[l * 15 + 5];
            int ctl5 = (tid >> 5) & 1;
            float pc5 = ctl5 ? p5 : 0.f;
            float qc5 = ctl5 ? (1.f - p5) : 1.f;
            sfor<2>([&](auto B14) {
                float val[16];
                sfor<4>([&](auto J) {
                    sfor<4>([&](auto V) {
                        scr[V.v * 1024 + tid] = r[B14.v * 16 + J.v * 4 + V.v];
                    });
                    __syncthreads();
                    if (wq == J.v) {
                        sfor<16>([&](auto G) { val[G.v] = scr[wv * 1024 + G.v * 64 + lane]; });
                    }
                    __syncthreads();
                });
                float vL[16];
                if (l > 0) {
                    const int srow = B14.v * 16 + wave;
                    sfor<16>([&](auto G) { vL[G.v] = ldsS[ladr(srow, G.v * 64 + lane)]; });
                } else {
                    sfor<16>([&](auto G) { vL[G.v] = 0.f; });
                }
                // rot q6..9 (G bits), both halves
                sfor<4>([&](auto Q) {
                    float4 m = Mg[l * NQ + 6 + Q.v];
                    sfor<16>([&](auto G) {
                        constexpr int h = 1 << Q.v;
                        if constexpr (!(G.v & h)) {
                            bf2(val[G.v], val[G.v | h], m);
                            bf2(vL[G.v],  vL[G.v | h],  m);
                        }
                    });
                });
                // rot q15: reg <-> lds pairs
                {
                    float4 m15 = Mg[l * NQ + 15];
                    sfor<16>([&](auto G) { bf2(val[G.v], vL[G.v], m15); });
                }
                // c5: ctrl b5 (lane), tgt b6 (G bit 0)
                sfor<16>([&](auto G) {
                    if constexpr (!(G.v & 1)) {
                        mixc(val[G.v], val[G.v | 1], qc5, pc5);
                        mixc(vL[G.v],  vL[G.v | 1],  qc5, pc5);
                    }
                });
                // c6..8: ctrl G bit CC, tgt G bit CC+1
                sfor<3>([&](auto CC) {
                    float p = pg[l * 15 + 6 + CC.v];
                    sfor<16>([&](auto G) {
                        constexpr int cm = 1 << CC.v;
                        constexpr int tm = 2 << CC.v;
                        if constexpr ((G.v & cm) && !(G.v & tm)) {
                            mix2(val[G.v], val[G.v | tm], p);
                            mix2(vL[G.v],  vL[G.v | tm],  p);
                        }
                    });
                });
                __syncthreads();   // all cross-reads of this 16-row region done
                sfor<16>([&](auto G) { ldsS[ladr(B14.v * 16 + G.v, tid)] = vL[G.v]; });
                sfor<16>([&](auto G) { r[B14.v * 16 + G.v] = val[G.v]; });
            });
        }

        // ======== T2: B->A transpose, fused c9..12 ========
        {
            float p9 = pg[l * 15 + 9];
            int ctl9 = (tid >> 9) & 1;
            float pc9 = ctl9 ? p9 : 0.f;
            float qc9 = ctl9 ? (1.f - p9) : 1.f;
            sfor<2>([&](auto B14) {
                float val[16];
                sfor<4>([&](auto J) {
                    sfor<4>([&](auto V) {
                        scr[V.v * 1024 + tid] = r[B14.v * 16 + J.v * 4 + V.v];
                    });
                    __syncthreads();
                    if (wq == J.v) {
                        sfor<16>([&](auto H) { val[H.v] = scr[wv * 1024 + H.v * 64 + lane]; });
                    }
                    __syncthreads();
                });
                float vL[16];
                {
                    const int srow = B14.v * 16 + wave;
                    sfor<16>([&](auto H) { vL[H.v] = ldsS[ladr(srow, H.v * 64 + lane)]; });
                }
                // c9: ctrl b9 (thread bit, layout A), tgt b10 (H bit 0)
                sfor<16>([&](auto H) {
                    if constexpr (!(H.v & 1)) {
                        mixc(val[H.v], val[H.v | 1], qc9, pc9);
                        mixc(vL[H.v],  vL[H.v | 1],  qc9, pc9);
                    }
                });
                // c10..12: ctrl H bit CC, tgt H bit CC+1
                sfor<3>([&](auto CC) {
                    float p = pg[l * 15 + 10 + CC.v];
                    sfor<16>([&](auto H) {
                        constexpr int cm = 1 << CC.v;
                        constexpr int tm = 2 << CC.v;
                        if constexpr ((H.v & cm) && !(H.v & tm)) {
                            mix2(val[H.v], val[H.v | tm], p);
                            mix2(vL[H.v],  vL[H.v | tm],  p);
                        }
                    });
                });
                __syncthreads();
                sfor<16>([&](auto H) { ldsS[ladr(B14.v * 16 + H.v, tid)] = vL[H.v]; });
                sfor<16>([&](auto H) { r[B14.v * 16 + H.v] = val[H.v]; });
            });
            __syncthreads();   // layer end: scatter visible to next S2 / output
        }
        // c13, c14 of this layer are DEFERRED: applied by the next layer's
        // S2 passA, or by the fused output pass after the last layer.
    }

    // ======== output: final c13/c14 (layer 2) fused with global write ========
    {
        float p13 = pg[2 * 15 + 13];
        float p14 = pg[2 * 15 + 14];
        // reg-half c13
        sfor<8>([&](auto K) { mix2(r[8 + K.v], r[24 + K.v], p13); });
        long long base = (long long)b * NSTATES;
        sfor<8>([&](auto W) {
            float t0 = ldsS[ladr(W.v,      tid)];
            float t1 = ldsS[ladr(W.v + 8,  tid)];
            float t2 = ldsS[ladr(W.v + 16, tid)];
            float t3 = ldsS[ladr(W.v + 24, tid)];
            mix2(t1, t3, p13);                  // c13 lds
            mix2(r[W.v + 16], t2, p14);         // c14
            mix2(r[W.v + 24], t3, p14);
            long long fb = base + 32768LL + (long long)(W.v * 1024) + tid;
            if (fb             < out_floats) out[fb]             = t0;
            if (fb + 8  * 1024 < out_floats) out[fb + 8  * 1024] = t1;
            if (fb + 16 * 1024 < out_floats) out[fb + 16 * 1024] = t2;
            if (fb + 24 * 1024 < out_floats) out[fb + 24 * 1024] = t3;
        });
        sfor<32>([&](auto J) {
            long long fi = base + (long long)(J.v * 1024) + tid;
            if (fi < out_floats) out[fi] = r[J.v];
        });
    }
}

extern "C" void kernel_launch(void* const* d_in, const int* in_sizes, int n_in,
                              void* d_out, int out_size, void* d_ws, size_t ws_size,
                              hipStream_t stream) {
    const float* x   = (const float*)d_in[0];
    const float* rot = (const float*)d_in[1];
    const float* ent = (const float*)d_in[2];
    const float* W1  = (const float*)d_in[3];
    const float* b1  = (const float*)d_in[4];
    const float* W2  = (const float*)d_in[5];
    const float* b2  = (const float*)d_in[6];

    qsim<<<BATCH, 1024, 0, stream>>>(x, rot, ent, W1, b1, W2, b2,
                                     (float*)d_out, (long long)out_size,
                                     in_sizes[0], in_sizes[1], in_sizes[2],
                                     in_sizes[3], in_sizes[4], in_sizes[5],
                                     in_sizes[6]);
}

// Round 7
// 216.629 us; speedup vs baseline: 1.2366x; 1.2366x over previous
//
#include <hip/hip_runtime.h>
#include <math.h>

#define NQ 16
#define NLAYERS 3
#define NSTATES 65536   // 2^16
#define BATCH 256

// Clamped global read: any harness/size mismatch becomes a wrong value,
// never an OOB fault.
__device__ __forceinline__ float rd(const float* __restrict__ p, int i, int n) {
    return p[i < n ? i : (n - 1)];
}

// ---------------------------------------------------------------------------
// static_for with compile-time indices (keeps every state subscript literal).
// ---------------------------------------------------------------------------
template <int I> struct IC { static constexpr int v = I; };

template <int I, int N, typename F>
__device__ __forceinline__ void sfor_i(F& f) {
    if constexpr (I < N) {
        f(IC<I>{});
        sfor_i<I + 1, N>(f);
    }
}
template <int N, typename F>
__device__ __forceinline__ void sfor(F&& f) { sfor_i<0, N>(f); }

// noisy-CNOT symmetric mix: a' = (1-p)a + pb ; b' = (1-p)b + pa
__device__ __forceinline__ void mix2(float& a, float& b, float p) {
    float na = (1.f - p) * a + p * b;
    float nb = (1.f - p) * b + p * a;
    a = na; b = nb;
}
// asymmetric variant with precomputed per-lane coeffs (lane-dependent ctrl)
__device__ __forceinline__ void mixc(float& a, float& b, float qc, float pc) {
    float na = qc * a + pc * b;
    float nb = qc * b + pc * a;
    a = na; b = nb;
}
// single-qubit butterfly on a pair (a0 = bit clear, a1 = bit set)
__device__ __forceinline__ void bf2(float& a0, float& a1, float4 m) {
    float n0 = m.x * a0 + m.y * a1;
    float n1 = m.z * a0 + m.w * a1;
    a0 = n0; a1 = n1;
}

// ---------------------------------------------------------------------------
// LDS state addressing: PHYSICAL STRIDE 1025 (1025 = 1 mod 32 -> per-row bank
// rotation identical to the R6 add-swizzle) with PLAIN column index.
//   natural (col = tid):       bank = (row + tid) & 31 -> 2 lanes/bank, free
//   row-segment (16 consec.):  16-lane groups cover 16 consecutive banks, free
// Crucially: multi-element accesses are base + compile-time immediates -> one
// address VGPR (R6's & 1023 wrap forced 16 live address registers -> spill).
// ---------------------------------------------------------------------------
__device__ __forceinline__ int ladr(int row, int col) {
    return row * 1025 + col;
}

// ---------------------------------------------------------------------------
// R7 = R6 structure minus register pressure (R6 re-spilled: FETCH 162 MB,
// WRITE 186 MB, dur 208us; cause = T1/T2 val+vL interleaved gating = 64 live
// state floats + 16 runtime LDS addrs in S3, over the immovable 64-VGPR wall).
//  - T1 serialized: gather val -> q6..9+c5..8 on val -> park in r -> load vL
//    -> q6..9+c5..8 on vL -> q15 pairs r/vL (q15 commutes with c5..8; exact).
//    Max live = r[32] + vL[16] = 48 (R5-proven level).
//  - T2 serialized: val pass, park, vL pass (c9..12 are b15-half-independent).
//  - stride-1025 addressing (see above).
// Layout A: row = (b14,b13..b10) (+reg slots for b15=0), col = tid = b9..b0.
// Layout B (between T1/T2): row = (b14, b9..b6), col = (b13..b10, b5..b0).
// ---------------------------------------------------------------------------
__global__
__attribute__((amdgpu_flat_work_group_size(1024, 1024)))
void qsim(const float* __restrict__ x,
          const float* __restrict__ rot,
          const float* __restrict__ ent,
          const float* __restrict__ W1,
          const float* __restrict__ b1,
          const float* __restrict__ W2,
          const float* __restrict__ b2,
          float* __restrict__ out,
          long long out_floats,
          int nx, int nrot, int nent, int nW1, int nb1, int nW2, int nb2) {
    const int tid  = threadIdx.x;
    const int b    = blockIdx.x;
    const int lane = tid & 63;
    const int wave = tid >> 6;
    const int wq   = (tid >> 8) & 3;  // transpose round selector
    const int wv   = (tid >> 6) & 3;  // transpose v-index

    __shared__ float  ldsS[32 * 1025];         // ~128 KiB: b15=1 half of state
    __shared__ float  scr[4 * 1024];           // 16 KiB transpose bounce
    __shared__ float4 Mg[NLAYERS * NQ];        // 48 gate matrices
    __shared__ float  pg[NLAYERS * (NQ - 1)];  // 45 CNOT mix probs
    __shared__ float  hidS[64];
    __shared__ float  hqS[16];

    // ---- Phase A: MLP hidden layer (64 threads) + sigmoid probs ----
    if (tid < 64) {
        float s = rd(b1, tid, nb1);
        for (int k = 0; k < 100; k++)
            s = fmaf(rd(x, b * 100 + k, nx), rd(W1, k * 64 + tid, nW1), s);
        hidS[tid] = fmaxf(s, 0.f);
    } else if (tid >= 64 && tid < 64 + NLAYERS * (NQ - 1)) {
        int i = tid - 64;
        pg[i] = 1.f / (1.f + expf(-rd(ent, i, nent)));
    }
    __syncthreads();

    // ---- Phase B: output layer hq (16 threads) ----
    if (tid < 16) {
        float s = rd(b2, tid, nb2);
#pragma unroll
        for (int i = 0; i < 64; i++)
            s = fmaf(hidS[i], rd(W2, i * 16 + tid, nW2), s);
        hqS[tid] = tanhf(s);
    }
    __syncthreads();

    // ---- Phase C: gate matrices (48 threads) ----
    if (tid < NLAYERS * NQ) {
        int q = tid & 15;
        float hv = hqS[q];
        float a0 = 0.5f * rd(rot, tid * 3 + 0, nrot) * hv;
        float a1 = 0.5f * rd(rot, tid * 3 + 1, nrot) * hv;
        float a2 = 0.5f * rd(rot, tid * 3 + 2, nrot) * hv;
        float cx = cosf(a0), sx = sinf(a0);
        float cy = cosf(a1), sy = sinf(a1);
        float cz = cosf(a2), sz = sinf(a2);
        Mg[tid] = make_float4(cx * cy * cz, -(sx * sy * sz),
                              sx * sy * cz,  cx * cy * sz);
    }
    __syncthreads();

    // ---- statevector init: |0...0> ----
    // ldsS deliberately NOT zero-initialized: layer 0 never reads it; T1's
    // scatter (l=0) writes every row before any read.
    float r[32];
    sfor<32>([&](auto J) { r[J.v] = 0.f; });
    if (tid == 0) r[0] = 1.f;

    for (int l = 0; l < NLAYERS; l++) {
        // ======== S2: prev-layer c13/c14 + this layer's q10..14 ========
        if (l > 0) {
            float p13p = pg[(l - 1) * 15 + 13];
            float p14p = pg[(l - 1) * 15 + 14];
            // reg-half c13 (b13=1): r[8..15] <-> r[24..31]
            sfor<8>([&](auto K) { mix2(r[8 + K.v], r[24 + K.v], p13p); });
            float4 m13 = Mg[l * NQ + 13];
            float4 m14 = Mg[l * NQ + 14];
            // passA: 4-row windows {w, w+8, w+16, w+24}: c13(lds), c14, q13, q14
            sfor<8>([&](auto W) {
                float t0 = ldsS[ladr(W.v,      tid)];
                float t1 = ldsS[ladr(W.v + 8,  tid)];
                float t2 = ldsS[ladr(W.v + 16, tid)];
                float t3 = ldsS[ladr(W.v + 24, tid)];
                mix2(t1, t3, p13p);               // c13 lds: rows 8..15<->24..31
                mix2(r[W.v + 16], t2, p14p);      // c14: reg s <-> lds row s (b14=1)
                mix2(r[W.v + 24], t3, p14p);
                bf2(t0, t1, m13); bf2(t2, t3, m13);   // q13
                bf2(t0, t2, m14); bf2(t1, t3, m14);   // q14
                ldsS[ladr(W.v,      tid)] = t0;
                ldsS[ladr(W.v + 8,  tid)] = t1;
                ldsS[ladr(W.v + 16, tid)] = t2;
                ldsS[ladr(W.v + 24, tid)] = t3;
            });
            // reg q13, q14 (after c14 touched r[16..31])
            sfor<8>([&](auto K) { bf2(r[K.v],      r[K.v + 8],  m13); });
            sfor<8>([&](auto K) { bf2(r[K.v + 16], r[K.v + 24], m13); });
            sfor<16>([&](auto K) { bf2(r[K.v], r[K.v + 16], m14); });
            // passB: 8-row windows: q10..12 (lds)
            sfor<4>([&](auto W) {
                float t[8];
                sfor<8>([&](auto K) { t[K.v] = ldsS[ladr(W.v * 8 + K.v, tid)]; });
                sfor<3>([&](auto QQ) {
                    float4 m = Mg[l * NQ + 10 + QQ.v];
                    sfor<8>([&](auto K) {
                        constexpr int h = 1 << QQ.v;
                        if constexpr (!(K.v & h)) bf2(t[K.v], t[K.v | h], m);
                    });
                });
                sfor<8>([&](auto K) { ldsS[ladr(W.v * 8 + K.v, tid)] = t[K.v]; });
            });
            // reg q10..12
            sfor<3>([&](auto QQ) {
                float4 m = Mg[l * NQ + 10 + QQ.v];
                sfor<32>([&](auto J) {
                    constexpr int h = 1 << QQ.v;
                    if constexpr (!(J.v & h)) bf2(r[J.v], r[J.v | h], m);
                });
            });
        } else {
            // l == 0: LDS half identically zero; reg-only q10..14
            sfor<5>([&](auto QQ) {
                float4 m = Mg[10 + QQ.v];
                sfor<32>([&](auto J) {
                    constexpr int h = 1 << QQ.v;
                    if constexpr (!(J.v & h)) bf2(r[J.v], r[J.v | h], m);
                });
            });
        }

        // ======== reg lane pass: rot q0..5 then cnot c0..4 (shfl) ========
#pragma unroll
        for (int q = 0; q < 6; q++) {
            float4 m = Mg[l * NQ + q];
            int bit = (tid >> q) & 1;
            float cown  = bit ? m.w : m.x;
            float cpart = bit ? m.z : m.y;
            sfor<4>([&](auto C) {
                sfor<8>([&](auto K) {
                    constexpr int j = C.v * 8 + K.v;
                    float part = __shfl_xor(r[j], 1 << q);
                    r[j] = cown * r[j] + cpart * part;
                });
                __builtin_amdgcn_sched_barrier(0);
            });
        }
#pragma unroll
        for (int c = 0; c < 5; c++) {
            float p = pg[l * 15 + c];
            int ctl = (tid >> c) & 1;
            float pc = ctl ? p : 0.f;
            float qc = ctl ? (1.f - p) : 1.f;
            sfor<4>([&](auto C) {
                sfor<8>([&](auto K) {
                    constexpr int j = C.v * 8 + K.v;
                    float f = __shfl_xor(r[j], 1 << (c + 1));
                    r[j] = qc * r[j] + pc * f;
                });
                __builtin_amdgcn_sched_barrier(0);
            });
        }

        // ======== S3: LDS-half lane gates via row-segment RMW ========
        // v[j] (j = b3..b0) are 16 CONSECUTIVE floats of one row (one addr
        // reg + immediate offsets). q0..3, c0..2 free VALU; q4/q5/c3/c4 shfl.
        if (l > 0) {
            __syncthreads();   // passB writes -> cross-column reads
            const int Rlow  = tid & 15;
            const int Cbase = tid & 0x3F0;
            const int bit4  = (tid >> 4) & 1;
            const int bit5  = (tid >> 5) & 1;
            sfor<2>([&](auto H) {
                const int R    = H.v * 16 + Rlow;
                const int base = ladr(R, Cbase);
                float v[16];
                sfor<16>([&](auto J) { v[J.v] = ldsS[base + J.v]; });
                // rot q0..3 (segment bits)
                sfor<4>([&](auto Q) {
                    float4 m = Mg[l * NQ + Q.v];
                    sfor<16>([&](auto J) {
                        constexpr int h = 1 << Q.v;
                        if constexpr (!(J.v & h)) bf2(v[J.v], v[J.v | h], m);
                    });
                });
                // rot q4 (lane bit 4)
                {
                    float4 m = Mg[l * NQ + 4];
                    float cown  = bit4 ? m.w : m.x;
                    float cpart = bit4 ? m.z : m.y;
                    sfor<2>([&](auto C) {
                        sfor<8>([&](auto K) {
                            constexpr int j = C.v * 8 + K.v;
                            float part = __shfl_xor(v[j], 16);
                            v[j] = cown * v[j] + cpart * part;
                        });
                        __builtin_amdgcn_sched_barrier(0);
                    });
                }
                // rot q5 (lane bit 5)
                {
                    float4 m = Mg[l * NQ + 5];
                    float cown  = bit5 ? m.w : m.x;
                    float cpart = bit5 ? m.z : m.y;
                    sfor<2>([&](auto C) {
                        sfor<8>([&](auto K) {
                            constexpr int j = C.v * 8 + K.v;
                            float part = __shfl_xor(v[j], 32);
                            v[j] = cown * v[j] + cpart * part;
                        });
                        __builtin_amdgcn_sched_barrier(0);
                    });
                }
                // c0..2 (within segment bits)
                {
                    float p = pg[l * 15 + 0];
                    sfor<16>([&](auto J) {
                        if constexpr ((J.v & 1) && !(J.v & 2)) mix2(v[J.v], v[J.v | 2], p);
                    });
                }
                {
                    float p = pg[l * 15 + 1];
                    sfor<16>([&](auto J) {
                        if constexpr ((J.v & 2) && !(J.v & 4)) mix2(v[J.v], v[J.v | 4], p);
                    });
                }
                {
                    float p = pg[l * 15 + 2];
                    sfor<16>([&](auto J) {
                        if constexpr ((J.v & 4) && !(J.v & 8)) mix2(v[J.v], v[J.v | 8], p);
                    });
                }
                // c3: ctrl b3 (segment), tgt b4 (lane): only j>=8 participate
                {
                    float p = pg[l * 15 + 3];
                    sfor<8>([&](auto K) {
                        constexpr int j = 8 + K.v;
                        float f = __shfl_xor(v[j], 16);
                        v[j] = (1.f - p) * v[j] + p * f;
                    });
                    __builtin_amdgcn_sched_barrier(0);
                }
                // c4: ctrl b4 (lane), tgt b5 (lane)
                {
                    float p = pg[l * 15 + 4];
                    float pc = bit4 ? p : 0.f;
                    float qc = bit4 ? (1.f - p) : 1.f;
                    sfor<2>([&](auto C) {
                        sfor<8>([&](auto K) {
                            constexpr int j = C.v * 8 + K.v;
                            float f = __shfl_xor(v[j], 32);
                            v[j] = qc * v[j] + pc * f;
                        });
                        __builtin_amdgcn_sched_barrier(0);
                    });
                }
                sfor<16>([&](auto J) { ldsS[base + J.v] = v[J.v]; });
            });
        }

        // ======== T1: A->B transpose, fused q6..9, c5..8, q15 ========
        // SERIALIZED val then vL (max live = r[32] + vL[16] = 48).
        {
            float p5 = pg[l * 15 + 5];
            int ctl5 = (tid >> 5) & 1;
            float pc5 = ctl5 ? p5 : 0.f;
            float qc5 = ctl5 ? (1.f - p5) : 1.f;
            sfor<2>([&](auto B14) {
                // --- reg half: gather via scratch ---
                float val[16];
                sfor<4>([&](auto J) {
                    sfor<4>([&](auto V) {
                        scr[V.v * 1024 + tid] = r[B14.v * 16 + J.v * 4 + V.v];
                    });
                    __syncthreads();
                    if (wq == J.v) {
                        sfor<16>([&](auto G) { val[G.v] = scr[wv * 1024 + G.v * 64 + lane]; });
                    }
                    __syncthreads();
                });
                // q6..9 on val (G bits)
                sfor<4>([&](auto Q) {
                    float4 m = Mg[l * NQ + 6 + Q.v];
                    sfor<16>([&](auto G) {
                        constexpr int h = 1 << Q.v;
                        if constexpr (!(G.v & h)) bf2(val[G.v], val[G.v | h], m);
                    });
                });
                // c5 (ctrl lane b5, tgt G bit 0), c6..8 on val
                sfor<16>([&](auto G) {
                    if constexpr (!(G.v & 1)) mixc(val[G.v], val[G.v | 1], qc5, pc5);
                });
                sfor<3>([&](auto CC) {
                    float p = pg[l * 15 + 6 + CC.v];
                    sfor<16>([&](auto G) {
                        constexpr int cm = 1 << CC.v;
                        constexpr int tm = 2 << CC.v;
                        if constexpr ((G.v & cm) && !(G.v & tm))
                            mix2(val[G.v], val[G.v | tm], p);
                    });
                });
                // park val in its (dead) r slots
                sfor<16>([&](auto G) { r[B14.v * 16 + G.v] = val[G.v]; });

                // --- lds half ---
                float vL[16];
                if (l > 0) {
                    const int srow = B14.v * 16 + wave;
                    const int base = ladr(srow, lane);
                    sfor<16>([&](auto G) { vL[G.v] = ldsS[base + G.v * 64]; });
                    sfor<4>([&](auto Q) {
                        float4 m = Mg[l * NQ + 6 + Q.v];
                        sfor<16>([&](auto G) {
                            constexpr int h = 1 << Q.v;
                            if constexpr (!(G.v & h)) bf2(vL[G.v], vL[G.v | h], m);
                        });
                    });
                    sfor<16>([&](auto G) {
                        if constexpr (!(G.v & 1)) mixc(vL[G.v], vL[G.v | 1], qc5, pc5);
                    });
                    sfor<3>([&](auto CC) {
                        float p = pg[l * 15 + 6 + CC.v];
                        sfor<16>([&](auto G) {
                            constexpr int cm = 1 << CC.v;
                            constexpr int tm = 2 << CC.v;
                            if constexpr ((G.v & cm) && !(G.v & tm))
                                mix2(vL[G.v], vL[G.v | tm], p);
                        });
                    });
                } else {
                    sfor<16>([&](auto G) { vL[G.v] = 0.f; });
                }
                // q15: reg <-> lds pairs (commutes with c5..8 -> exact)
                {
                    float4 m15 = Mg[l * NQ + 15];
                    sfor<16>([&](auto G) { bf2(r[B14.v * 16 + G.v], vL[G.v], m15); });
                }
                __syncthreads();   // all cross-reads of this 16-row region done
                sfor<16>([&](auto G) { ldsS[ladr(B14.v * 16 + G.v, tid)] = vL[G.v]; });
            });
        }

        // ======== T2: B->A transpose, fused c9..12 (SERIALIZED) ========
        {
            float p9 = pg[l * 15 + 9];
            int ctl9 = (tid >> 9) & 1;
            float pc9 = ctl9 ? p9 : 0.f;
            float qc9 = ctl9 ? (1.f - p9) : 1.f;
            sfor<2>([&](auto B14) {
                // --- reg half ---
                float val[16];
                sfor<4>([&](auto J) {
                    sfor<4>([&](auto V) {
                        scr[V.v * 1024 + tid] = r[B14.v * 16 + J.v * 4 + V.v];
                    });
                    __syncthreads();
                    if (wq == J.v) {
                        sfor<16>([&](auto H) { val[H.v] = scr[wv * 1024 + H.v * 64 + lane]; });
                    }
                    __syncthreads();
                });
                // c9 (ctrl thread b9, tgt H bit 0), c10..12 on val
                sfor<16>([&](auto H) {
                    if constexpr (!(H.v & 1)) mixc(val[H.v], val[H.v | 1], qc9, pc9);
                });
                sfor<3>([&](auto CC) {
                    float p = pg[l * 15 + 10 + CC.v];
                    sfor<16>([&](auto H) {
                        constexpr int cm = 1 << CC.v;
                        constexpr int tm = 2 << CC.v;
                        if constexpr ((H.v & cm) && !(H.v & tm))
                            mix2(val[H.v], val[H.v | tm], p);
                    });
                });
                sfor<16>([&](auto H) { r[B14.v * 16 + H.v] = val[H.v]; });

                // --- lds half ---
                float vL[16];
                {
                    const int srow = B14.v * 16 + wave;
                    const int base = ladr(srow, lane);
                    sfor<16>([&](auto H) { vL[H.v] = ldsS[base + H.v * 64]; });
                }
                sfor<16>([&](auto H) {
                    if constexpr (!(H.v & 1)) mixc(vL[H.v], vL[H.v | 1], qc9, pc9);
                });
                sfor<3>([&](auto CC) {
                    float p = pg[l * 15 + 10 + CC.v];
                    sfor<16>([&](auto H) {
                        constexpr int cm = 1 << CC.v;
                        constexpr int tm = 2 << CC.v;
                        if constexpr ((H.v & cm) && !(H.v & tm))
                            mix2(vL[H.v], vL[H.v | tm], p);
                    });
                });
                __syncthreads();
                sfor<16>([&](auto H) { ldsS[ladr(B14.v * 16 + H.v, tid)] = vL[H.v]; });
            });
            __syncthreads();   // layer end: scatter visible to next S2 / output
        }
        // c13, c14 of this layer are DEFERRED: applied by the next layer's
        // S2 passA, or by the fused output pass after the last layer.
    }

    // ======== output: final c13/c14 (layer 2) fused with global write ========
    {
        float p13 = pg[2 * 15 + 13];
        float p14 = pg[2 * 15 + 14];
        // reg-half c13
        sfor<8>([&](auto K) { mix2(r[8 + K.v], r[24 + K.v], p13); });
        long long base = (long long)b * NSTATES;
        sfor<8>([&](auto W) {
            float t0 = ldsS[ladr(W.v,      tid)];
            float t1 = ldsS[ladr(W.v + 8,  tid)];
            float t2 = ldsS[ladr(W.v + 16, tid)];
            float t3 = ldsS[ladr(W.v + 24, tid)];
            mix2(t1, t3, p13);                  // c13 lds
            mix2(r[W.v + 16], t2, p14);         // c14
            mix2(r[W.v + 24], t3, p14);
            long long fb = base + 32768LL + (long long)(W.v * 1024) + tid;
            if (fb             < out_floats) out[fb]             = t0;
            if (fb + 8  * 1024 < out_floats) out[fb + 8  * 1024] = t1;
            if (fb + 16 * 1024 < out_floats) out[fb + 16 * 1024] = t2;
            if (fb + 24 * 1024 < out_floats) out[fb + 24 * 1024] = t3;
        });
        sfor<32>([&](auto J) {
            long long fi = base + (long long)(J.v * 1024) + tid;
            if (fi < out_floats) out[fi] = r[J.v];
        });
    }
}

extern "C" void kernel_launch(void* const* d_in, const int* in_sizes, int n_in,
                              void* d_out, int out_size, void* d_ws, size_t ws_size,
                              hipStream_t stream) {
    const float* x   = (const float*)d_in[0];
    const float* rot = (const float*)d_in[1];
    const float* ent = (const float*)d_in[2];
    const float* W1  = (const float*)d_in[3];
    const float* b1  = (const float*)d_in[4];
    const float* W2  = (const float*)d_in[5];
    const float* b2  = (const float*)d_in[6];

    qsim<<<BATCH, 1024, 0, stream>>>(x, rot, ent, W1, b1, W2, b2,
                                     (float*)d_out, (long long)out_size,
                                     in_sizes[0], in_sizes[1], in_sizes[2],
                                     in_sizes[3], in_sizes[4], in_sizes[5],
                                     in_sizes[6]);
}

// Round 8
// 214.901 us; speedup vs baseline: 1.2465x; 1.0080x over previous
//
#include <hip/hip_runtime.h>
#include <math.h>

#define NQ 16
#define NLAYERS 3
#define NSTATES 65536   // 2^16
#define BATCH 256

// Clamped global read: any harness/size mismatch becomes a wrong value,
// never an OOB fault.
__device__ __forceinline__ float rd(const float* __restrict__ p, int i, int n) {
    return p[i < n ? i : (n - 1)];
}

// ---------------------------------------------------------------------------
// static_for with compile-time indices (keeps every state subscript literal).
// ---------------------------------------------------------------------------
template <int I> struct IC { static constexpr int v = I; };

template <int I, int N, typename F>
__device__ __forceinline__ void sfor_i(F& f) {
    if constexpr (I < N) {
        f(IC<I>{});
        sfor_i<I + 1, N>(f);
    }
}
template <int N, typename F>
__device__ __forceinline__ void sfor(F&& f) { sfor_i<0, N>(f); }

// noisy-CNOT symmetric mix: a' = (1-p)a + pb ; b' = (1-p)b + pa
__device__ __forceinline__ void mix2(float& a, float& b, float p) {
    float na = (1.f - p) * a + p * b;
    float nb = (1.f - p) * b + p * a;
    a = na; b = nb;
}
// asymmetric variant with precomputed per-lane coeffs (lane-dependent ctrl)
__device__ __forceinline__ void mixc(float& a, float& b, float qc, float pc) {
    float na = qc * a + pc * b;
    float nb = qc * b + pc * a;
    a = na; b = nb;
}
// single-qubit butterfly on a pair (a0 = bit clear, a1 = bit set)
__device__ __forceinline__ void bf2(float& a0, float& a1, float4 m) {
    float n0 = m.x * a0 + m.y * a1;
    float n1 = m.z * a0 + m.w * a1;
    a0 = n0; a1 = n1;
}

// ---------------------------------------------------------------------------
// LDS state addressing: physical stride 1025 (== 1 mod 32 -> per-row bank
// rotation). Natural col=tid: 2 lanes/bank (free). Row-segment (16 consec.):
// 16 consecutive banks per 16-lane group (free). Multi-element accesses are
// base + compile-time immediates -> one address VGPR.
// ---------------------------------------------------------------------------
__device__ __forceinline__ int ladr(int row, int col) {
    return row * 1025 + col;
}

// ---------------------------------------------------------------------------
// R8 = R7 with three exact-commutation restructures + pressure trims:
//  1. q10..13 moved from S2 into T2 (both halves hold H=b13..b10 there ->
//     free VALU butterflies). S2 passB (96 b32/thread-layer) DELETED.
//     S2 passA keeps only prev-c13, prev-c14, q14.
//  2. S3 parks r[28..31] in scr (idle there; S3-entry barrier stops
//     forwarding) -> S3 live 60 -> ~52, under the immovable 64-VGPR wall.
//  3. shfl chunks 8 -> 4 (halve in-flight bpermute dests); sched_barrier
//     after vL load batches (no cross-phase load hoisting).
// Layout A: reg slots = b14..b10 (b15=0), LDS rows = b14..b10 (b15=1),
//           col = tid = b9..b0.
// Layout B (between T1/T2): row = (b14, b9..b6), col = (b13..b10, b5..b0).
// Gate schedule (exact commutations, verified):
//   S2: prev-c13, prev-c14, q14 | lane: q0..5, c0..4 (reg) | S3: same (lds)
//   T1: q6..9, c5, c6..8, q15   | T2: q10..13, c9, c10..12 | c13/c14 deferred.
// ---------------------------------------------------------------------------
__global__
__attribute__((amdgpu_flat_work_group_size(1024, 1024)))
void qsim(const float* __restrict__ x,
          const float* __restrict__ rot,
          const float* __restrict__ ent,
          const float* __restrict__ W1,
          const float* __restrict__ b1,
          const float* __restrict__ W2,
          const float* __restrict__ b2,
          float* __restrict__ out,
          long long out_floats,
          int nx, int nrot, int nent, int nW1, int nb1, int nW2, int nb2) {
    const int tid  = threadIdx.x;
    const int b    = blockIdx.x;
    const int lane = tid & 63;
    const int wave = tid >> 6;
    const int wq   = (tid >> 8) & 3;  // transpose round selector
    const int wv   = (tid >> 6) & 3;  // transpose v-index

    __shared__ float  ldsS[32 * 1025];         // ~128 KiB: b15=1 half of state
    __shared__ float  scr[4 * 1024];           // 16 KiB transpose bounce / park
    __shared__ float4 Mg[NLAYERS * NQ];        // 48 gate matrices
    __shared__ float  pg[NLAYERS * (NQ - 1)];  // 45 CNOT mix probs
    __shared__ float  hidS[64];
    __shared__ float  hqS[16];

    // ---- Phase A: MLP hidden layer (64 threads) + sigmoid probs ----
    if (tid < 64) {
        float s = rd(b1, tid, nb1);
        for (int k = 0; k < 100; k++)
            s = fmaf(rd(x, b * 100 + k, nx), rd(W1, k * 64 + tid, nW1), s);
        hidS[tid] = fmaxf(s, 0.f);
    } else if (tid >= 64 && tid < 64 + NLAYERS * (NQ - 1)) {
        int i = tid - 64;
        pg[i] = 1.f / (1.f + expf(-rd(ent, i, nent)));
    }
    __syncthreads();

    // ---- Phase B: output layer hq (16 threads) ----
    if (tid < 16) {
        float s = rd(b2, tid, nb2);
#pragma unroll
        for (int i = 0; i < 64; i++)
            s = fmaf(hidS[i], rd(W2, i * 16 + tid, nW2), s);
        hqS[tid] = tanhf(s);
    }
    __syncthreads();

    // ---- Phase C: gate matrices (48 threads) ----
    if (tid < NLAYERS * NQ) {
        int q = tid & 15;
        float hv = hqS[q];
        float a0 = 0.5f * rd(rot, tid * 3 + 0, nrot) * hv;
        float a1 = 0.5f * rd(rot, tid * 3 + 1, nrot) * hv;
        float a2 = 0.5f * rd(rot, tid * 3 + 2, nrot) * hv;
        float cx = cosf(a0), sx = sinf(a0);
        float cy = cosf(a1), sy = sinf(a1);
        float cz = cosf(a2), sz = sinf(a2);
        Mg[tid] = make_float4(cx * cy * cz, -(sx * sy * sz),
                              sx * sy * cz,  cx * cy * sz);
    }
    __syncthreads();

    // ---- statevector init: |0...0> ----
    // ldsS deliberately NOT zero-initialized: layer 0 never reads it; T1's
    // scatter (l=0, via q15) writes every row before any read.
    float r[32];
    sfor<32>([&](auto J) { r[J.v] = 0.f; });
    if (tid == 0) r[0] = 1.f;

    for (int l = 0; l < NLAYERS; l++) {
        // ======== S2: prev c13/c14 + q14 (quadrant-pair row pass) ========
        if (l > 0) {
            float p13p = pg[(l - 1) * 15 + 13];
            float p14p = pg[(l - 1) * 15 + 14];
            float4 m14 = Mg[l * NQ + 14];
            sfor<8>([&](auto W) {
                float t0 = ldsS[ladr(W.v,      tid)];
                float t1 = ldsS[ladr(W.v + 8,  tid)];
                float t2 = ldsS[ladr(W.v + 16, tid)];
                float t3 = ldsS[ladr(W.v + 24, tid)];
                // prev c13 (ctrl b13): reg pair + lds pair
                mix2(r[8 + W.v], r[24 + W.v], p13p);
                mix2(t1, t3, p13p);
                // prev c14 (ctrl b14, tgt b15): reg(b14=1) <-> lds(b14=1)
                mix2(r[16 + W.v], t2, p14p);
                mix2(r[24 + W.v], t3, p14p);
                // q14 butterfly (b14)
                bf2(r[W.v], r[16 + W.v], m14);
                bf2(r[8 + W.v], r[24 + W.v], m14);
                bf2(t0, t2, m14);
                bf2(t1, t3, m14);
                ldsS[ladr(W.v,      tid)] = t0;
                ldsS[ladr(W.v + 8,  tid)] = t1;
                ldsS[ladr(W.v + 16, tid)] = t2;
                ldsS[ladr(W.v + 24, tid)] = t3;
            });
        } else {
            // l == 0: LDS half identically zero; q14 reg-only
            float4 m14 = Mg[14];
            sfor<16>([&](auto K) { bf2(r[K.v], r[K.v + 16], m14); });
        }

        // ======== reg lane pass: rot q0..5 then cnot c0..4 (shfl) ========
#pragma unroll
        for (int q = 0; q < 6; q++) {
            float4 m = Mg[l * NQ + q];
            int bit = (tid >> q) & 1;
            float cown  = bit ? m.w : m.x;
            float cpart = bit ? m.z : m.y;
            sfor<8>([&](auto C) {
                sfor<4>([&](auto K) {
                    constexpr int j = C.v * 4 + K.v;
                    float part = __shfl_xor(r[j], 1 << q);
                    r[j] = cown * r[j] + cpart * part;
                });
                __builtin_amdgcn_sched_barrier(0);
            });
        }
#pragma unroll
        for (int c = 0; c < 5; c++) {
            float p = pg[l * 15 + c];
            int ctl = (tid >> c) & 1;
            float pc = ctl ? p : 0.f;
            float qc = ctl ? (1.f - p) : 1.f;
            sfor<8>([&](auto C) {
                sfor<4>([&](auto K) {
                    constexpr int j = C.v * 4 + K.v;
                    float f = __shfl_xor(r[j], 1 << (c + 1));
                    r[j] = qc * r[j] + pc * f;
                });
                __builtin_amdgcn_sched_barrier(0);
            });
        }

        // ======== S3: LDS-half lane gates via row-segment RMW ========
        // v[j] (j = b3..b0) = 16 consecutive floats of one row. q0..3, c0..2
        // free VALU; q4/q5/c3/c4 shfl. r[28..31] parked in scr (idle there).
        if (l > 0) {
            sfor<4>([&](auto V) { scr[V.v * 1024 + tid] = r[28 + V.v]; });
            __syncthreads();   // passA column-writes -> row-segment reads
            const int Rlow  = tid & 15;
            const int Cbase = tid & 0x3F0;
            const int bit4  = (tid >> 4) & 1;
            const int bit5  = (tid >> 5) & 1;
            sfor<2>([&](auto H) {
                const int R    = H.v * 16 + Rlow;
                const int base = ladr(R, Cbase);
                float v[16];
                sfor<16>([&](auto J) { v[J.v] = ldsS[base + J.v]; });
                // rot q0..3 (segment bits)
                sfor<4>([&](auto Q) {
                    float4 m = Mg[l * NQ + Q.v];
                    sfor<16>([&](auto J) {
                        constexpr int h = 1 << Q.v;
                        if constexpr (!(J.v & h)) bf2(v[J.v], v[J.v | h], m);
                    });
                });
                // rot q4 (lane bit 4)
                {
                    float4 m = Mg[l * NQ + 4];
                    float cown  = bit4 ? m.w : m.x;
                    float cpart = bit4 ? m.z : m.y;
                    sfor<4>([&](auto C) {
                        sfor<4>([&](auto K) {
                            constexpr int j = C.v * 4 + K.v;
                            float part = __shfl_xor(v[j], 16);
                            v[j] = cown * v[j] + cpart * part;
                        });
                        __builtin_amdgcn_sched_barrier(0);
                    });
                }
                // rot q5 (lane bit 5)
                {
                    float4 m = Mg[l * NQ + 5];
                    float cown  = bit5 ? m.w : m.x;
                    float cpart = bit5 ? m.z : m.y;
                    sfor<4>([&](auto C) {
                        sfor<4>([&](auto K) {
                            constexpr int j = C.v * 4 + K.v;
                            float part = __shfl_xor(v[j], 32);
                            v[j] = cown * v[j] + cpart * part;
                        });
                        __builtin_amdgcn_sched_barrier(0);
                    });
                }
                // c0..2 (within segment bits)
                {
                    float p = pg[l * 15 + 0];
                    sfor<16>([&](auto J) {
                        if constexpr ((J.v & 1) && !(J.v & 2)) mix2(v[J.v], v[J.v | 2], p);
                    });
                }
                {
                    float p = pg[l * 15 + 1];
                    sfor<16>([&](auto J) {
                        if constexpr ((J.v & 2) && !(J.v & 4)) mix2(v[J.v], v[J.v | 4], p);
                    });
                }
                {
                    float p = pg[l * 15 + 2];
                    sfor<16>([&](auto J) {
                        if constexpr ((J.v & 4) && !(J.v & 8)) mix2(v[J.v], v[J.v | 8], p);
                    });
                }
                // c3: ctrl b3 (segment), tgt b4 (lane): only j>=8 participate
                {
                    float p = pg[l * 15 + 3];
                    sfor<2>([&](auto C) {
                        sfor<4>([&](auto K) {
                            constexpr int j = 8 + C.v * 4 + K.v;
                            float f = __shfl_xor(v[j], 16);
                            v[j] = (1.f - p) * v[j] + p * f;
                        });
                        __builtin_amdgcn_sched_barrier(0);
                    });
                }
                // c4: ctrl b4 (lane), tgt b5 (lane)
                {
                    float p = pg[l * 15 + 4];
                    float pc = bit4 ? p : 0.f;
                    float qc = bit4 ? (1.f - p) : 1.f;
                    sfor<4>([&](auto C) {
                        sfor<4>([&](auto K) {
                            constexpr int j = C.v * 4 + K.v;
                            float f = __shfl_xor(v[j], 32);
                            v[j] = qc * v[j] + pc * f;
                        });
                        __builtin_amdgcn_sched_barrier(0);
                    });
                }
                sfor<16>([&](auto J) { ldsS[base + J.v] = v[J.v]; });
            });
            // restore parked regs (own scr slots; same-thread in-order)
            sfor<4>([&](auto V) { r[28 + V.v] = scr[V.v * 1024 + tid]; });
        }

        // ======== T1: A->B transpose, fused q6..9, c5..8, q15 ========
        // Serialized val then vL (max live = r[32] + vL[16] = 48).
        {
            float p5 = pg[l * 15 + 5];
            int ctl5 = (tid >> 5) & 1;
            float pc5 = ctl5 ? p5 : 0.f;
            float qc5 = ctl5 ? (1.f - p5) : 1.f;
            sfor<2>([&](auto B14) {
                // --- reg half: gather via scratch ---
                float val[16];
                sfor<4>([&](auto J) {
                    sfor<4>([&](auto V) {
                        scr[V.v * 1024 + tid] = r[B14.v * 16 + J.v * 4 + V.v];
                    });
                    __syncthreads();
                    if (wq == J.v) {
                        sfor<16>([&](auto G) { val[G.v] = scr[wv * 1024 + G.v * 64 + lane]; });
                    }
                    __syncthreads();
                });
                // q6..9 on val (G bits)
                sfor<4>([&](auto Q) {
                    float4 m = Mg[l * NQ + 6 + Q.v];
                    sfor<16>([&](auto G) {
                        constexpr int h = 1 << Q.v;
                        if constexpr (!(G.v & h)) bf2(val[G.v], val[G.v | h], m);
                    });
                });
                // c5 (ctrl lane b5, tgt G bit 0), c6..8 on val
                sfor<16>([&](auto G) {
                    if constexpr (!(G.v & 1)) mixc(val[G.v], val[G.v | 1], qc5, pc5);
                });
                sfor<3>([&](auto CC) {
                    float p = pg[l * 15 + 6 + CC.v];
                    sfor<16>([&](auto G) {
                        constexpr int cm = 1 << CC.v;
                        constexpr int tm = 2 << CC.v;
                        if constexpr ((G.v & cm) && !(G.v & tm))
                            mix2(val[G.v], val[G.v | tm], p);
                    });
                });
                // park val in its (dead) r slots
                sfor<16>([&](auto G) { r[B14.v * 16 + G.v] = val[G.v]; });

                // --- lds half ---
                float vL[16];
                if (l > 0) {
                    const int srow = B14.v * 16 + wave;
                    const int base = ladr(srow, lane);
                    sfor<16>([&](auto G) { vL[G.v] = ldsS[base + G.v * 64]; });
                    __builtin_amdgcn_sched_barrier(0);
                    sfor<4>([&](auto Q) {
                        float4 m = Mg[l * NQ + 6 + Q.v];
                        sfor<16>([&](auto G) {
                            constexpr int h = 1 << Q.v;
                            if constexpr (!(G.v & h)) bf2(vL[G.v], vL[G.v | h], m);
                        });
                    });
                    sfor<16>([&](auto G) {
                        if constexpr (!(G.v & 1)) mixc(vL[G.v], vL[G.v | 1], qc5, pc5);
                    });
                    sfor<3>([&](auto CC) {
                        float p = pg[l * 15 + 6 + CC.v];
                        sfor<16>([&](auto G) {
                            constexpr int cm = 1 << CC.v;
                            constexpr int tm = 2 << CC.v;
                            if constexpr ((G.v & cm) && !(G.v & tm))
                                mix2(vL[G.v], vL[G.v | tm], p);
                        });
                    });
                } else {
                    sfor<16>([&](auto G) { vL[G.v] = 0.f; });
                }
                // q15: reg <-> lds pairs (commutes with c5..8 -> exact)
                {
                    float4 m15 = Mg[l * NQ + 15];
                    sfor<16>([&](auto G) { bf2(r[B14.v * 16 + G.v], vL[G.v], m15); });
                }
                __syncthreads();   // all cross-reads of this 16-row region done
                sfor<16>([&](auto G) { ldsS[ladr(B14.v * 16 + G.v, tid)] = vL[G.v]; });
            });
        }

        // ======== T2: B->A transpose, fused q10..13, c9..12 ========
        {
            float p9 = pg[l * 15 + 9];
            int ctl9 = (tid >> 9) & 1;
            float pc9 = ctl9 ? p9 : 0.f;
            float qc9 = ctl9 ? (1.f - p9) : 1.f;
            sfor<2>([&](auto B14) {
                // --- reg half ---
                float val[16];
                sfor<4>([&](auto J) {
                    sfor<4>([&](auto V) {
                        scr[V.v * 1024 + tid] = r[B14.v * 16 + J.v * 4 + V.v];
                    });
                    __syncthreads();
                    if (wq == J.v) {
                        sfor<16>([&](auto H) { val[H.v] = scr[wv * 1024 + H.v * 64 + lane]; });
                    }
                    __syncthreads();
                });
                // q10..13 (H bits) -- moved here from S2 (free VALU)
                sfor<4>([&](auto QQ) {
                    float4 m = Mg[l * NQ + 10 + QQ.v];
                    sfor<16>([&](auto H) {
                        constexpr int h = 1 << QQ.v;
                        if constexpr (!(H.v & h)) bf2(val[H.v], val[H.v | h], m);
                    });
                });
                // c9 (ctrl thread b9, tgt H bit 0), c10..12 on val
                sfor<16>([&](auto H) {
                    if constexpr (!(H.v & 1)) mixc(val[H.v], val[H.v | 1], qc9, pc9);
                });
                sfor<3>([&](auto CC) {
                    float p = pg[l * 15 + 10 + CC.v];
                    sfor<16>([&](auto H) {
                        constexpr int cm = 1 << CC.v;
                        constexpr int tm = 2 << CC.v;
                        if constexpr ((H.v & cm) && !(H.v & tm))
                            mix2(val[H.v], val[H.v | tm], p);
                    });
                });
                sfor<16>([&](auto H) { r[B14.v * 16 + H.v] = val[H.v]; });

                // --- lds half ---
                float vL[16];
                {
                    const int srow = B14.v * 16 + wave;
                    const int base = ladr(srow, lane);
                    sfor<16>([&](auto H) { vL[H.v] = ldsS[base + H.v * 64]; });
                    __builtin_amdgcn_sched_barrier(0);
                }
                sfor<4>([&](auto QQ) {
                    float4 m = Mg[l * NQ + 10 + QQ.v];
                    sfor<16>([&](auto H) {
                        constexpr int h = 1 << QQ.v;
                        if constexpr (!(H.v & h)) bf2(vL[H.v], vL[H.v | h], m);
                    });
                });
                sfor<16>([&](auto H) {
                    if constexpr (!(H.v & 1)) mixc(vL[H.v], vL[H.v | 1], qc9, pc9);
                });
                sfor<3>([&](auto CC) {
                    float p = pg[l * 15 + 10 + CC.v];
                    sfor<16>([&](auto H) {
                        constexpr int cm = 1 << CC.v;
                        constexpr int tm = 2 << CC.v;
                        if constexpr ((H.v & cm) && !(H.v & tm))
                            mix2(vL[H.v], vL[H.v | tm], p);
                    });
                });
                __syncthreads();
                sfor<16>([&](auto H) { ldsS[ladr(B14.v * 16 + H.v, tid)] = vL[H.v]; });
            });
            __syncthreads();   // layer end: scatter visible to next S2 / output
        }
        // c13, c14 of this layer are DEFERRED: applied by the next layer's
        // S2 passA, or by the fused output pass after the last layer.
    }

    // ======== output: final c13/c14 (layer 2) fused with global write ========
    {
        float p13 = pg[2 * 15 + 13];
        float p14 = pg[2 * 15 + 14];
        // reg-half c13
        sfor<8>([&](auto K) { mix2(r[8 + K.v], r[24 + K.v], p13); });
        long long base = (long long)b * NSTATES;
        sfor<8>([&](auto W) {
            float t0 = ldsS[ladr(W.v,      tid)];
            float t1 = ldsS[ladr(W.v + 8,  tid)];
            float t2 = ldsS[ladr(W.v + 16, tid)];
            float t3 = ldsS[ladr(W.v + 24, tid)];
            mix2(t1, t3, p13);                  // c13 lds
            mix2(r[W.v + 16], t2, p14);         // c14
            mix2(r[W.v + 24], t3, p14);
            long long fb = base + 32768LL + (long long)(W.v * 1024) + tid;
            if (fb             < out_floats) out[fb]             = t0;
            if (fb + 8  * 1024 < out_floats) out[fb + 8  * 1024] = t1;
            if (fb + 16 * 1024 < out_floats) out[fb + 16 * 1024] = t2;
            if (fb + 24 * 1024 < out_floats) out[fb + 24 * 1024] = t3;
        });
        sfor<32>([&](auto J) {
            long long fi = base + (long long)(J.v * 1024) + tid;
            if (fi < out_floats) out[fi] = r[J.v];
        });
    }
}

extern "C" void kernel_launch(void* const* d_in, const int* in_sizes, int n_in,
                              void* d_out, int out_size, void* d_ws, size_t ws_size,
                              hipStream_t stream) {
    const float* x   = (const float*)d_in[0];
    const float* rot = (const float*)d_in[1];
    const float* ent = (const float*)d_in[2];
    const float* W1  = (const float*)d_in[3];
    const float* b1  = (const float*)d_in[4];
    const float* W2  = (const float*)d_in[5];
    const float* b2  = (const float*)d_in[6];

    qsim<<<BATCH, 1024, 0, stream>>>(x, rot, ent, W1, b1, W2, b2,
                                     (float*)d_out, (long long)out_size,
                                     in_sizes[0], in_sizes[1], in_sizes[2],
                                     in_sizes[3], in_sizes[4], in_sizes[5],
                                     in_sizes[6]);
}